// Round 1
// baseline (427.730 us; speedup 1.0000x reference)
//
#include <hip/hip_runtime.h>
#include <stdint.h>

typedef __attribute__((ext_vector_type(8))) short short8;
typedef __attribute__((ext_vector_type(4))) float f32x4;
typedef __attribute__((ext_vector_type(2))) unsigned int uint2v;

#define C0 228
#define C1 111
#define C2 51
#define KP 448          // padded channel space: [0,256)=b0, [256,384)=b1, [384,448)=b2
#define RS 456          // LDS row stride in bf16 elems (912 B -> 4-bank row skew)
#define NPIX 64
#define HWP 65536

__device__ __forceinline__ unsigned short f2bf(float f) {
  unsigned u = __float_as_uint(f);
  u += 0x7FFFu + ((u >> 16) & 1u);          // RNE
  return (unsigned short)(u >> 16);
}
__device__ __forceinline__ float bf2f(unsigned v) {
  return __uint_as_float(v << 16);
}

// padded channel -> real output channel (or -1 for pad)
__device__ __forceinline__ int out_chan(int c) {
  if (c < 228) return c;
  if (c < 256) return -1;
  if (c < 367) return 228 + (c - 256);
  if (c < 384) return -1;
  if (c < 435) return 339 + (c - 384);
  return -1;
}

__global__ void crf_prep(
    const float* __restrict__ w01, const float* __restrict__ w02,
    const float* __restrict__ w10, const float* __restrict__ w12,
    const float* __restrict__ w20, const float* __restrict__ w21,
    const float* __restrict__ b01, const float* __restrict__ b02,
    const float* __restrict__ b10, const float* __restrict__ b12,
    const float* __restrict__ b20, const float* __restrict__ b21,
    unsigned short* __restrict__ Wrow, float* __restrict__ bbig) {
  int idx = blockIdx.x * 256 + threadIdx.x;
  if (idx >= KP * KP) return;
  int m = idx / KP;
  int k = idx - m * KP;
  int bm, lm, bk, lk, Ck;
  bool mr, kr;
  if (m < 256)      { bm = 0; lm = m;       mr = lm < C0; }
  else if (m < 384) { bm = 1; lm = m - 256; mr = lm < C1; }
  else              { bm = 2; lm = m - 384; mr = lm < C2; }
  if (k < 256)      { bk = 0; lk = k;       Ck = C0; kr = lk < C0; }
  else if (k < 384) { bk = 1; lk = k - 256; Ck = C1; kr = lk < C1; }
  else              { bk = 2; lk = k - 384; Ck = C2; kr = lk < C2; }
  float v = 0.f;
  if (bm != bk && mr && kr) {
    const float* w;
    if (bk == 0)      w = (bm == 1) ? w01 : w02;
    else if (bk == 1) w = (bm == 0) ? w10 : w12;
    else              w = (bm == 0) ? w20 : w21;
    v = w[lm * Ck + lk];               // w_{j,i}[cout=lm][cin=lk]
  }
  Wrow[idx] = f2bf(v);
  if (idx < KP) {
    float bv = 0.f;
    int c = idx;
    if (c < 228)                  bv = b10[c] + b20[c];
    else if (c >= 256 && c < 367) bv = b01[c - 256] + b21[c - 256];
    else if (c >= 384 && c < 435) bv = b02[c - 384] + b12[c - 384];
    bbig[idx] = bv;
  }
}

// 64 pixels per workgroup, 4 waves. Wave w owns cout-tiles {w, w+4, ..., w+24}.
// MFMA: A = Wrow[cout][k] (global/L2), B = h[k][pixel] (LDS), D = [cout][pixel].
__global__ __launch_bounds__(256, 2) void crf_main(
    const float* __restrict__ x0, const float* __restrict__ x1,
    const float* __restrict__ x2,
    const unsigned short* __restrict__ Wrow,
    const float* __restrict__ bbig,
    const float* __restrict__ pa,
    float* __restrict__ out) {
  __shared__ unsigned short hL[NPIX][RS];   // 58368 B -> 2 wg/CU
  const int lane = threadIdx.x & 63;
  const int wave = threadIdx.x >> 6;
  const int tile = blockIdx.x;
  const int b = tile >> 10;                 // 1024 tiles per batch image
  const int pp0 = (tile & 1023) << 6;
  const float apar = pa[0];

  // ---- stage-in: x (fp32, channel-major) -> hL[pixel][padded channel] bf16 ----
  // wave handles channel-groups {wave + 4*gi}, 8 channels each; lane = pixel.
  #pragma unroll
  for (int gi = 0; gi < 14; ++gi) {
    const int c0 = (wave + gi * 4) * 8;
    short8 pk;
    #pragma unroll
    for (int cc = 0; cc < 8; ++cc) {
      const int c = c0 + cc;
      float v = 0.f;
      if (c < 228)
        v = x0[(((size_t)(b * C0 + c)) << 16) + pp0 + lane];
      else if (c >= 256 && c < 367)
        v = x1[(((size_t)(b * C1 + (c - 256))) << 16) + pp0 + lane];
      else if (c >= 384 && c < 435)
        v = x2[(((size_t)(b * C2 + (c - 384))) << 16) + pp0 + lane];
      pk[cc] = (short)f2bf(v);
    }
    *reinterpret_cast<short8*>(&hL[lane][c0]) = pk;
  }
  __syncthreads();

  const int l15 = lane & 15;
  const int lq = lane >> 4;

  for (int it = 0; it < 2; ++it) {
    f32x4 acc[7][4];
    #pragma unroll
    for (int t = 0; t < 7; ++t)
      #pragma unroll
      for (int n = 0; n < 4; ++n)
        acc[t][n] = (f32x4){0.f, 0.f, 0.f, 0.f};

    for (int ks = 0; ks < 14; ++ks) {
      const int kb = (ks < 8) ? 0 : ((ks < 12) ? 1 : 2);
      const int kcol = ks * 32 + (lq << 3);
      short8 bq[4];
      #pragma unroll
      for (int n = 0; n < 4; ++n)
        bq[n] = *reinterpret_cast<const short8*>(&hL[n * 16 + l15][kcol]);
      #pragma unroll
      for (int t = 0; t < 7; ++t) {
        const int bm = (t < 4) ? 0 : ((t < 6) ? 1 : 2);
        if (bm == kb) continue;           // diagonal (zero) block: skip
        const int mt = wave + 4 * t;
        const short8 aq = *reinterpret_cast<const short8*>(
            Wrow + (mt * 16 + l15) * KP + kcol);
        #pragma unroll
        for (int n = 0; n < 4; ++n)
          acc[t][n] =
              __builtin_amdgcn_mfma_f32_16x16x32_bf16(aq, bq[n], acc[t][n], 0, 0, 0);
      }
    }
    __syncthreads();   // all K-loop reads of hL complete before overwrites

    if (it == 0) {
      // h1 = relu(h0 + prelu(binary + bias)); write back bf16 into same buffer
      #pragma unroll
      for (int t = 0; t < 7; ++t) {
        const int cb = (wave + 4 * t) * 16 + (lq << 2);
        const f32x4 bias = *reinterpret_cast<const f32x4*>(bbig + cb);
        #pragma unroll
        for (int n = 0; n < 4; ++n) {
          const int p = n * 16 + l15;
          uint2v ho = *reinterpret_cast<const uint2v*>(&hL[p][cb]);
          const float hof[4] = {bf2f(ho[0] & 0xFFFFu), bf2f(ho[0] >> 16),
                                bf2f(ho[1] & 0xFFFFu), bf2f(ho[1] >> 16)};
          unsigned short nb[4];
          #pragma unroll
          for (int r = 0; r < 4; ++r) {
            float v = acc[t][n][r] + bias[r];
            float pr = (v >= 0.f) ? v : apar * v;
            nb[r] = f2bf(fmaxf(hof[r] + pr, 0.f));
          }
          uint2v pw;
          pw[0] = (unsigned)nb[0] | ((unsigned)nb[1] << 16);
          pw[1] = (unsigned)nb[2] | ((unsigned)nb[3] << 16);
          *reinterpret_cast<uint2v*>(&hL[p][cb]) = pw;   // own channels only
        }
      }
      __syncthreads();
    } else {
      // final: out = relu(h1 + prelu(binary + bias)), fp32 to global
      #pragma unroll
      for (int t = 0; t < 7; ++t) {
        const int cb = (wave + 4 * t) * 16 + (lq << 2);
        const f32x4 bias = *reinterpret_cast<const f32x4*>(bbig + cb);
        #pragma unroll
        for (int n = 0; n < 4; ++n) {
          const int p = n * 16 + l15;
          uint2v ho = *reinterpret_cast<const uint2v*>(&hL[p][cb]);
          const float hof[4] = {bf2f(ho[0] & 0xFFFFu), bf2f(ho[0] >> 16),
                                bf2f(ho[1] & 0xFFFFu), bf2f(ho[1] >> 16)};
          #pragma unroll
          for (int r = 0; r < 4; ++r) {
            const int c = cb + r;
            const int o = out_chan(c);
            float v = acc[t][n][r] + bias[r];
            float pr = (v >= 0.f) ? v : apar * v;
            float hn = fmaxf(hof[r] + pr, 0.f);
            if (o >= 0)
              out[(((size_t)(b * 390 + o)) << 16) + pp0 + p] = hn;
          }
        }
      }
    }
  }
}

extern "C" void kernel_launch(void* const* d_in, const int* in_sizes, int n_in,
                              void* d_out, int out_size, void* d_ws, size_t ws_size,
                              hipStream_t stream) {
  const float* x0  = (const float*)d_in[0];
  const float* x1  = (const float*)d_in[1];
  const float* x2  = (const float*)d_in[2];
  const float* w01 = (const float*)d_in[3];
  const float* b01 = (const float*)d_in[4];
  const float* w02 = (const float*)d_in[5];
  const float* b02 = (const float*)d_in[6];
  const float* w10 = (const float*)d_in[7];
  const float* b10 = (const float*)d_in[8];
  const float* w12 = (const float*)d_in[9];
  const float* b12 = (const float*)d_in[10];
  const float* w20 = (const float*)d_in[11];
  const float* b20 = (const float*)d_in[12];
  const float* w21 = (const float*)d_in[13];
  const float* b21 = (const float*)d_in[14];
  const float* pa  = (const float*)d_in[15];

  unsigned short* Wrow = (unsigned short*)d_ws;                       // 448*448*2 B
  float* bbig = (float*)((char*)d_ws + (size_t)KP * KP * 2);          // +1792 B

  crf_prep<<<dim3((KP * KP + 255) / 256), dim3(256), 0, stream>>>(
      w01, w02, w10, w12, w20, w21, b01, b02, b10, b12, b20, b21, Wrow, bbig);
  crf_main<<<dim3(2048), dim3(256), 0, stream>>>(x0, x1, x2, Wrow, bbig, pa,
                                                 (float*)d_out);
}

// Round 2
// 238.514 us; speedup vs baseline: 1.7933x; 1.7933x over previous
//
#include <hip/hip_runtime.h>
#include <stdint.h>

typedef __attribute__((ext_vector_type(8))) short short8;
typedef __attribute__((ext_vector_type(4))) float f32x4;
typedef __attribute__((ext_vector_type(2))) unsigned int uint2v;

#define C0 228
#define C1 111
#define C2 51
#define KP 448          // padded channel space: [0,256)=b0, [256,384)=b1, [384,448)=b2
#define RS 456          // LDS row stride in bf16 elems (912 B -> 4-bank row skew)
#define NPIX 64
#define HWP 65536

__device__ __forceinline__ unsigned short f2bf(float f) {
  unsigned u = __float_as_uint(f);
  u += 0x7FFFu + ((u >> 16) & 1u);          // RNE
  return (unsigned short)(u >> 16);
}
__device__ __forceinline__ float bf2f(unsigned v) {
  return __uint_as_float(v << 16);
}

// padded channel -> real output channel (or -1 for pad)
__device__ __forceinline__ int out_chan(int c) {
  if (c < 228) return c;
  if (c < 256) return -1;
  if (c < 367) return 228 + (c - 256);
  if (c < 384) return -1;
  if (c < 435) return 339 + (c - 384);
  return -1;
}

__global__ void crf_prep(
    const float* __restrict__ w01, const float* __restrict__ w02,
    const float* __restrict__ w10, const float* __restrict__ w12,
    const float* __restrict__ w20, const float* __restrict__ w21,
    const float* __restrict__ b01, const float* __restrict__ b02,
    const float* __restrict__ b10, const float* __restrict__ b12,
    const float* __restrict__ b20, const float* __restrict__ b21,
    unsigned short* __restrict__ Wrow, float* __restrict__ bbig) {
  int idx = blockIdx.x * 256 + threadIdx.x;
  if (idx >= KP * KP) return;
  int m = idx / KP;
  int k = idx - m * KP;
  int bm, lm, bk, lk, Ck;
  bool mr, kr;
  if (m < 256)      { bm = 0; lm = m;       mr = lm < C0; }
  else if (m < 384) { bm = 1; lm = m - 256; mr = lm < C1; }
  else              { bm = 2; lm = m - 384; mr = lm < C2; }
  if (k < 256)      { bk = 0; lk = k;       Ck = C0; kr = lk < C0; }
  else if (k < 384) { bk = 1; lk = k - 256; Ck = C1; kr = lk < C1; }
  else              { bk = 2; lk = k - 384; Ck = C2; kr = lk < C2; }
  float v = 0.f;
  if (bm != bk && mr && kr) {
    const float* w;
    if (bk == 0)      w = (bm == 1) ? w01 : w02;
    else if (bk == 1) w = (bm == 0) ? w10 : w12;
    else              w = (bm == 0) ? w20 : w21;
    v = w[lm * Ck + lk];               // w_{j,i}[cout=lm][cin=lk]
  }
  Wrow[idx] = f2bf(v);
  if (idx < KP) {
    float bv = 0.f;
    int c = idx;
    if (c < 228)                  bv = b10[c] + b20[c];
    else if (c >= 256 && c < 367) bv = b01[c - 256] + b21[c - 256];
    else if (c >= 384 && c < 435) bv = b02[c - 384] + b12[c - 384];
    bbig[idx] = bv;
  }
}

// 64 pixels per workgroup, 4 waves. Wave w owns cout-tiles {w, w+4, ..., w+24}.
// MFMA: A = Wrow[cout][k] (global/L2), B = h[k][pixel] (LDS), D = [cout][pixel].
__global__ __launch_bounds__(256, 2) void crf_main(
    const float* __restrict__ x0, const float* __restrict__ x1,
    const float* __restrict__ x2,
    const unsigned short* __restrict__ Wrow,
    const float* __restrict__ bbig,
    const float* __restrict__ pa,
    float* __restrict__ out) {
  __shared__ unsigned short hL[NPIX][RS];   // 58368 B -> 2 wg/CU
  const int lane = threadIdx.x & 63;
  const int wave = threadIdx.x >> 6;
  const int tile = blockIdx.x;
  const int b = tile >> 10;                 // 1024 tiles per batch image
  const int pp0 = (tile & 1023) << 6;
  const float apar = pa[0];

  // ---- stage-in: x (fp32, channel-major) -> hL[pixel][padded channel] bf16 ----
  // wave handles channel-groups {wave + 4*gi}, 8 channels each; lane = pixel.
  // Non-temporal: x is streamed exactly once -- keep it from evicting Wrow in L2.
  #pragma unroll
  for (int gi = 0; gi < 14; ++gi) {
    const int c0 = (wave + gi * 4) * 8;
    short8 pk;
    #pragma unroll
    for (int cc = 0; cc < 8; ++cc) {
      const int c = c0 + cc;
      float v = 0.f;
      if (c < 228)
        v = __builtin_nontemporal_load(
            x0 + (((size_t)(b * C0 + c)) << 16) + pp0 + lane);
      else if (c >= 256 && c < 367)
        v = __builtin_nontemporal_load(
            x1 + (((size_t)(b * C1 + (c - 256))) << 16) + pp0 + lane);
      else if (c >= 384 && c < 435)
        v = __builtin_nontemporal_load(
            x2 + (((size_t)(b * C2 + (c - 384))) << 16) + pp0 + lane);
      pk[cc] = (short)f2bf(v);
    }
    *reinterpret_cast<short8*>(&hL[lane][c0]) = pk;
  }
  __syncthreads();

  const int l15 = lane & 15;
  const int lq = lane >> 4;

  #pragma unroll
  for (int it = 0; it < 2; ++it) {
    f32x4 acc[7][4];
    #pragma unroll
    for (int t = 0; t < 7; ++t)
      #pragma unroll
      for (int n = 0; n < 4; ++n)
        acc[t][n] = (f32x4){0.f, 0.f, 0.f, 0.f};

    #pragma unroll
    for (int ks = 0; ks < 14; ++ks) {
      const int kb = (ks < 8) ? 0 : ((ks < 12) ? 1 : 2);
      const int kcol = ks * 32 + (lq << 3);
      short8 bq[4];
      #pragma unroll
      for (int n = 0; n < 4; ++n)
        bq[n] = *reinterpret_cast<const short8*>(&hL[n * 16 + l15][kcol]);
      #pragma unroll
      for (int t = 0; t < 7; ++t) {
        const int bm = (t < 4) ? 0 : ((t < 6) ? 1 : 2);
        if (bm == kb) continue;           // diagonal (zero) block: skip
        const int mt = wave + 4 * t;
        const short8 aq = *reinterpret_cast<const short8*>(
            Wrow + (mt * 16 + l15) * KP + kcol);
        #pragma unroll
        for (int n = 0; n < 4; ++n)
          acc[t][n] =
              __builtin_amdgcn_mfma_f32_16x16x32_bf16(aq, bq[n], acc[t][n], 0, 0, 0);
      }
    }
    __syncthreads();   // all K-loop reads of hL complete before overwrites

    if (it == 0) {
      // h1 = relu(h0 + prelu(binary + bias)); write back bf16 into same buffer
      #pragma unroll
      for (int t = 0; t < 7; ++t) {
        const int cb = (wave + 4 * t) * 16 + (lq << 2);
        const f32x4 bias = *reinterpret_cast<const f32x4*>(bbig + cb);
        #pragma unroll
        for (int n = 0; n < 4; ++n) {
          const int p = n * 16 + l15;
          uint2v ho = *reinterpret_cast<const uint2v*>(&hL[p][cb]);
          const float hof[4] = {bf2f(ho[0] & 0xFFFFu), bf2f(ho[0] >> 16),
                                bf2f(ho[1] & 0xFFFFu), bf2f(ho[1] >> 16)};
          unsigned short nb[4];
          #pragma unroll
          for (int r = 0; r < 4; ++r) {
            float v = acc[t][n][r] + bias[r];
            float pr = (v >= 0.f) ? v : apar * v;
            nb[r] = f2bf(fmaxf(hof[r] + pr, 0.f));
          }
          uint2v pw;
          pw[0] = (unsigned)nb[0] | ((unsigned)nb[1] << 16);
          pw[1] = (unsigned)nb[2] | ((unsigned)nb[3] << 16);
          *reinterpret_cast<uint2v*>(&hL[p][cb]) = pw;   // own channels only
        }
      }
      __syncthreads();
    } else {
      // final: out = relu(h1 + prelu(binary + bias)), fp32 to global (streaming)
      #pragma unroll
      for (int t = 0; t < 7; ++t) {
        const int cb = (wave + 4 * t) * 16 + (lq << 2);
        const f32x4 bias = *reinterpret_cast<const f32x4*>(bbig + cb);
        #pragma unroll
        for (int n = 0; n < 4; ++n) {
          const int p = n * 16 + l15;
          uint2v ho = *reinterpret_cast<const uint2v*>(&hL[p][cb]);
          const float hof[4] = {bf2f(ho[0] & 0xFFFFu), bf2f(ho[0] >> 16),
                                bf2f(ho[1] & 0xFFFFu), bf2f(ho[1] >> 16)};
          #pragma unroll
          for (int r = 0; r < 4; ++r) {
            const int c = cb + r;
            const int o = out_chan(c);
            float v = acc[t][n][r] + bias[r];
            float pr = (v >= 0.f) ? v : apar * v;
            float hn = fmaxf(hof[r] + pr, 0.f);
            if (o >= 0)
              __builtin_nontemporal_store(
                  hn, out + (((size_t)(b * 390 + o)) << 16) + pp0 + p);
          }
        }
      }
    }
  }
}

extern "C" void kernel_launch(void* const* d_in, const int* in_sizes, int n_in,
                              void* d_out, int out_size, void* d_ws, size_t ws_size,
                              hipStream_t stream) {
  const float* x0  = (const float*)d_in[0];
  const float* x1  = (const float*)d_in[1];
  const float* x2  = (const float*)d_in[2];
  const float* w01 = (const float*)d_in[3];
  const float* b01 = (const float*)d_in[4];
  const float* w02 = (const float*)d_in[5];
  const float* b02 = (const float*)d_in[6];
  const float* w10 = (const float*)d_in[7];
  const float* b10 = (const float*)d_in[8];
  const float* w12 = (const float*)d_in[9];
  const float* b12 = (const float*)d_in[10];
  const float* w20 = (const float*)d_in[11];
  const float* b20 = (const float*)d_in[12];
  const float* w21 = (const float*)d_in[13];
  const float* b21 = (const float*)d_in[14];
  const float* pa  = (const float*)d_in[15];

  unsigned short* Wrow = (unsigned short*)d_ws;                       // 448*448*2 B
  float* bbig = (float*)((char*)d_ws + (size_t)KP * KP * 2);          // +1792 B

  crf_prep<<<dim3((KP * KP + 255) / 256), dim3(256), 0, stream>>>(
      w01, w02, w10, w12, w20, w21, b01, b02, b10, b12, b20, b21, Wrow, bbig);
  crf_main<<<dim3(2048), dim3(256), 0, stream>>>(x0, x1, x2, Wrow, bbig, pa,
                                                 (float*)d_out);
}

// Round 3
// 201.753 us; speedup vs baseline: 2.1201x; 1.1822x over previous
//
#include <hip/hip_runtime.h>
#include <stdint.h>

typedef __attribute__((ext_vector_type(8))) short short8;
typedef __attribute__((ext_vector_type(4))) float f32x4;
typedef __attribute__((ext_vector_type(2))) unsigned int uint2v;

#define C0 228
#define C1 111
#define C2 51
#define KP 448          // padded channel space: [0,256)=b0, [256,384)=b1, [384,448)=b2
#define RS 456          // LDS row stride in bf16 elems (912 B -> 4-dword bank skew)
#define NPIX 64

__device__ __forceinline__ unsigned short f2bf(float f) {
  unsigned u = __float_as_uint(f);
  u += 0x7FFFu + ((u >> 16) & 1u);          // RNE
  return (unsigned short)(u >> 16);
}
__device__ __forceinline__ float bf2f(unsigned v) {
  return __uint_as_float(v << 16);
}

// padded channel -> real output channel (or -1 for pad)
__device__ __forceinline__ int out_chan(int c) {
  if (c < 228) return c;
  if (c < 256) return -1;
  if (c < 367) return 228 + (c - 256);
  if (c < 384) return -1;
  if (c < 435) return 339 + (c - 384);
  return -1;
}

__global__ void crf_prep(
    const float* __restrict__ w01, const float* __restrict__ w02,
    const float* __restrict__ w10, const float* __restrict__ w12,
    const float* __restrict__ w20, const float* __restrict__ w21,
    const float* __restrict__ b01, const float* __restrict__ b02,
    const float* __restrict__ b10, const float* __restrict__ b12,
    const float* __restrict__ b20, const float* __restrict__ b21,
    unsigned short* __restrict__ Wrow, float* __restrict__ bbig) {
  int idx = blockIdx.x * 256 + threadIdx.x;
  if (idx >= KP * KP) return;
  int m = idx / KP;
  int k = idx - m * KP;
  int bm, lm, bk, lk, Ck;
  bool mr, kr;
  if (m < 256)      { bm = 0; lm = m;       mr = lm < C0; }
  else if (m < 384) { bm = 1; lm = m - 256; mr = lm < C1; }
  else              { bm = 2; lm = m - 384; mr = lm < C2; }
  if (k < 256)      { bk = 0; lk = k;       Ck = C0; kr = lk < C0; }
  else if (k < 384) { bk = 1; lk = k - 256; Ck = C1; kr = lk < C1; }
  else              { bk = 2; lk = k - 384; Ck = C2; kr = lk < C2; }
  float v = 0.f;
  if (bm != bk && mr && kr) {
    const float* w;
    if (bk == 0)      w = (bm == 1) ? w01 : w02;
    else if (bk == 1) w = (bm == 0) ? w10 : w12;
    else              w = (bm == 0) ? w20 : w21;
    v = w[lm * Ck + lk];               // w_{j,i}[cout=lm][cin=lk]
  }
  Wrow[idx] = f2bf(v);
  if (idx < KP) {
    float bv = 0.f;
    int c = idx;
    if (c < 228)                  bv = b10[c] + b20[c];
    else if (c >= 256 && c < 367) bv = b01[c - 256] + b21[c - 256];
    else if (c >= 384 && c < 435) bv = b02[c - 384] + b12[c - 384];
    bbig[idx] = bv;
  }
}

// 64 pixels per workgroup, 8 waves (512 thr). Wave w owns cout-tiles mt = w + 8t'
// (t'=0..3; waves 4..7 have only 3 valid tiles since 28 tiles total).
// Block id per t' is compile-time: {b0, b0, b1, b2}.
// MFMA: A = Wrow[cout][k] (global/L2), B = h[k][pixel] (LDS), D = [cout][pixel].
__global__ __launch_bounds__(512, 4) void crf_main(
    const float* __restrict__ x0, const float* __restrict__ x1,
    const float* __restrict__ x2,
    const unsigned short* __restrict__ Wrow,
    const float* __restrict__ bbig,
    const float* __restrict__ pa,
    float* __restrict__ out) {
  __shared__ unsigned short hL[NPIX][RS];   // 58368 B -> 2 wg/CU
  const int lane = threadIdx.x & 63;
  const int wave = threadIdx.x >> 6;
  const int tile = blockIdx.x;
  const int b = tile >> 10;                 // 1024 tiles per batch image
  const int pp0 = (tile & 1023) << 6;
  const float apar = pa[0];
  const bool has3 = (wave < 4);             // is tile t'=3 (mt = wave+24) valid?

  // ---- stage-in: x (fp32, channel-major) -> hL[pixel][padded channel] bf16 ----
  // wave handles channel-groups {wave + 8*g}, 8 channels each; lane = pixel.
  // Non-temporal: x is streamed exactly once -- keep it from evicting Wrow in L2.
  #pragma unroll
  for (int g = 0; g < 7; ++g) {
    const int c0 = (wave + g * 8) * 8;
    short8 pk;
    #pragma unroll
    for (int cc = 0; cc < 8; ++cc) {
      const int c = c0 + cc;
      float v = 0.f;
      if (c < 228)
        v = __builtin_nontemporal_load(
            x0 + (((size_t)(b * C0 + c)) << 16) + pp0 + lane);
      else if (c >= 256 && c < 367)
        v = __builtin_nontemporal_load(
            x1 + (((size_t)(b * C1 + (c - 256))) << 16) + pp0 + lane);
      else if (c >= 384 && c < 435)
        v = __builtin_nontemporal_load(
            x2 + (((size_t)(b * C2 + (c - 384))) << 16) + pp0 + lane);
      pk[cc] = (short)f2bf(v);
    }
    *reinterpret_cast<short8*>(&hL[lane][c0]) = pk;
  }
  __syncthreads();

  const int l15 = lane & 15;
  const int lq = lane >> 4;

  #pragma unroll
  for (int it = 0; it < 2; ++it) {
    f32x4 acc[4][4];
    #pragma unroll
    for (int t = 0; t < 4; ++t)
      #pragma unroll
      for (int n = 0; n < 4; ++n)
        acc[t][n] = (f32x4){0.f, 0.f, 0.f, 0.f};

    #pragma unroll
    for (int ks = 0; ks < 14; ++ks) {
      const int kb = (ks < 8) ? 0 : ((ks < 12) ? 1 : 2);
      const int kcol = ks * 32 + (lq << 3);
      short8 bq[4];
      #pragma unroll
      for (int n = 0; n < 4; ++n)
        bq[n] = *reinterpret_cast<const short8*>(&hL[n * 16 + l15][kcol]);
      #pragma unroll
      for (int t = 0; t < 4; ++t) {
        const int bm = (t < 2) ? 0 : ((t < 3) ? 1 : 2);   // compile-time per t
        if (bm == kb) continue;           // diagonal (zero) block: skip
        if (t == 3 && !has3) continue;    // waves 4..7: no 4th tile (uniform)
        const int mt = wave + 8 * t;
        const short8 aq = *reinterpret_cast<const short8*>(
            Wrow + (mt * 16 + l15) * KP + kcol);
        #pragma unroll
        for (int n = 0; n < 4; ++n)
          acc[t][n] =
              __builtin_amdgcn_mfma_f32_16x16x32_bf16(aq, bq[n], acc[t][n], 0, 0, 0);
      }
    }
    __syncthreads();   // all K-loop reads of hL complete before overwrites

    if (it == 0) {
      // h1 = relu(h0 + prelu(binary + bias)); write back bf16 into same buffer
      #pragma unroll
      for (int t = 0; t < 4; ++t) {
        if (t == 3 && !has3) continue;
        const int cb = (wave + 8 * t) * 16 + (lq << 2);
        const f32x4 bias = *reinterpret_cast<const f32x4*>(bbig + cb);
        #pragma unroll
        for (int n = 0; n < 4; ++n) {
          const int p = n * 16 + l15;
          uint2v ho = *reinterpret_cast<const uint2v*>(&hL[p][cb]);
          const float hof[4] = {bf2f(ho[0] & 0xFFFFu), bf2f(ho[0] >> 16),
                                bf2f(ho[1] & 0xFFFFu), bf2f(ho[1] >> 16)};
          unsigned short nb[4];
          #pragma unroll
          for (int r = 0; r < 4; ++r) {
            float v = acc[t][n][r] + bias[r];
            float pr = (v >= 0.f) ? v : apar * v;
            nb[r] = f2bf(fmaxf(hof[r] + pr, 0.f));
          }
          uint2v pw;
          pw[0] = (unsigned)nb[0] | ((unsigned)nb[1] << 16);
          pw[1] = (unsigned)nb[2] | ((unsigned)nb[3] << 16);
          *reinterpret_cast<uint2v*>(&hL[p][cb]) = pw;   // own channels only
        }
      }
      __syncthreads();
    } else {
      // final: out = relu(h1 + prelu(binary + bias)), fp32 to global (streaming)
      #pragma unroll
      for (int t = 0; t < 4; ++t) {
        if (t == 3 && !has3) continue;
        const int cb = (wave + 8 * t) * 16 + (lq << 2);
        const f32x4 bias = *reinterpret_cast<const f32x4*>(bbig + cb);
        #pragma unroll
        for (int n = 0; n < 4; ++n) {
          const int p = n * 16 + l15;
          uint2v ho = *reinterpret_cast<const uint2v*>(&hL[p][cb]);
          const float hof[4] = {bf2f(ho[0] & 0xFFFFu), bf2f(ho[0] >> 16),
                                bf2f(ho[1] & 0xFFFFu), bf2f(ho[1] >> 16)};
          #pragma unroll
          for (int r = 0; r < 4; ++r) {
            const int c = cb + r;
            const int o = out_chan(c);
            float v = acc[t][n][r] + bias[r];
            float pr = (v >= 0.f) ? v : apar * v;
            float hn = fmaxf(hof[r] + pr, 0.f);
            if (o >= 0)
              __builtin_nontemporal_store(
                  hn, out + (((size_t)(b * 390 + o)) << 16) + pp0 + p);
          }
        }
      }
    }
  }
}

extern "C" void kernel_launch(void* const* d_in, const int* in_sizes, int n_in,
                              void* d_out, int out_size, void* d_ws, size_t ws_size,
                              hipStream_t stream) {
  const float* x0  = (const float*)d_in[0];
  const float* x1  = (const float*)d_in[1];
  const float* x2  = (const float*)d_in[2];
  const float* w01 = (const float*)d_in[3];
  const float* b01 = (const float*)d_in[4];
  const float* w02 = (const float*)d_in[5];
  const float* b02 = (const float*)d_in[6];
  const float* w10 = (const float*)d_in[7];
  const float* b10 = (const float*)d_in[8];
  const float* w12 = (const float*)d_in[9];
  const float* b12 = (const float*)d_in[10];
  const float* w20 = (const float*)d_in[11];
  const float* b20 = (const float*)d_in[12];
  const float* w21 = (const float*)d_in[13];
  const float* b21 = (const float*)d_in[14];
  const float* pa  = (const float*)d_in[15];

  unsigned short* Wrow = (unsigned short*)d_ws;                       // 448*448*2 B
  float* bbig = (float*)((char*)d_ws + (size_t)KP * KP * 2);          // +1792 B

  crf_prep<<<dim3((KP * KP + 255) / 256), dim3(256), 0, stream>>>(
      w01, w02, w10, w12, w20, w21, b01, b02, b10, b12, b20, b21, Wrow, bbig);
  crf_main<<<dim3(2048), dim3(512), 0, stream>>>(x0, x1, x2, Wrow, bbig, pa,
                                                 (float*)d_out);
}